// Round 1
// baseline (137.452 us; speedup 1.0000x reference)
//
#include <hip/hip_runtime.h>
#include <hip/hip_bf16.h>

// SpatialAttention: B=4 T=12 N=512 D=128, 8 heads x d=16.
// Pipeline: [gemm_k<0> x3] qkv proj -> [attn_k] flash attention -> [gemm_k<1>] o-proj relu -> [gemm_k<2>] final.

typedef unsigned short u16;
typedef __bf16 bf16_t;
typedef bf16_t bf16x8 __attribute__((ext_vector_type(8)));
typedef float f32x4 __attribute__((ext_vector_type(4)));
typedef u16 u16x8 __attribute__((ext_vector_type(8)));
typedef u16 u16x4 __attribute__((ext_vector_type(4)));

__device__ __forceinline__ u16 f2bf(float f) {
    unsigned u = __builtin_bit_cast(unsigned, f);
    u += 0x7FFFu + ((u >> 16) & 1u);   // round-to-nearest-even
    return (u16)(u >> 16);
}

__device__ __forceinline__ f32x4 mfma16(bf16x8 a, bf16x8 b, f32x4 c) {
    return __builtin_amdgcn_mfma_f32_16x16x32_bf16(a, b, c, 0, 0, 0);
}

// ---------------------------------------------------------------------------
// Generic 128x128-tile GEMM, N=128 fixed. 4 waves, each computes 64x64.
// MODE 0: A = concat(x,ste) f32 (K=256), out = relu(.)+bias -> bf16 per-head scatter
// MODE 1: A = bf16 (K=128),            out = relu(.)+bias -> bf16 row-major
// MODE 2: A = bf16 (K=128),            out = (.)+bias     -> f32 row-major
// ---------------------------------------------------------------------------
template<int MODE>
__global__ __launch_bounds__(256) void gemm_k(const void* __restrict__ A0,
                                              const void* __restrict__ A1,
                                              const float* __restrict__ W,
                                              const float* __restrict__ bias,
                                              void* __restrict__ Out)
{
    constexpr int KTOT = (MODE == 0) ? 256 : 128;
    __shared__ u16 As[128][40];   // A tile bf16, padded stride (80B) to avoid bank conflicts
    __shared__ u16 Bs[128][40];   // W^T tile: Bs[n][k]

    const int tid  = threadIdx.x;
    const int wave = tid >> 6;
    const int lane = tid & 63;
    const int g    = lane >> 4;
    const int lc   = lane & 15;
    const int wr   = wave >> 1;
    const int wc   = wave & 1;
    const long mbase = (long)blockIdx.x * 128;

    const f32x4 ZERO4 = {0.f, 0.f, 0.f, 0.f};
    f32x4 acc[4][4];
#pragma unroll
    for (int m = 0; m < 4; ++m)
#pragma unroll
        for (int n = 0; n < 4; ++n) acc[m][n] = ZERO4;

    for (int k0 = 0; k0 < KTOT; k0 += 32) {
        // ---- stage A tile (128 rows x 32 k) as bf16
        if constexpr (MODE == 0) {
            const float* src = (k0 < 128) ? (const float*)A0 : (const float*)A1;
            const int kk = k0 & 127;
#pragma unroll
            for (int i = 0; i < 4; ++i) {
                int pos = tid + i * 256;            // 0..1023
                int r = pos >> 3, c4 = pos & 7;     // col = 4*c4
                f32x4 v = *(const f32x4*)(src + (mbase + r) * 128 + kk + c4 * 4);
                u16x4 hv;
                hv[0] = f2bf(v[0]); hv[1] = f2bf(v[1]); hv[2] = f2bf(v[2]); hv[3] = f2bf(v[3]);
                *(u16x4*)&As[r][c4 * 4] = hv;
            }
        } else {
            const u16* src = (const u16*)A0;
#pragma unroll
            for (int i = 0; i < 2; ++i) {
                int pos = tid + i * 256;            // 0..511
                int r = pos >> 2, c8 = pos & 3;     // col = 8*c8
                *(u16x8*)&As[r][c8 * 8] = *(const u16x8*)(src + (mbase + r) * 128 + k0 + c8 * 8);
            }
        }
        // ---- stage W^T tile: Bs[n][k] = bf16(W[k0+k][n])
#pragma unroll
        for (int i = 0; i < 16; ++i) {
            int pos = tid + i * 256;                // 0..4095
            int k = pos >> 7, n = pos & 127;
            Bs[n][k] = f2bf(W[(long)(k0 + k) * 128 + n]);
        }
        __syncthreads();

        bf16x8 af[4], bfr[4];
#pragma unroll
        for (int m = 0; m < 4; ++m)
            af[m] = *(const bf16x8*)&As[wr * 64 + m * 16 + lc][g * 8];
#pragma unroll
        for (int n = 0; n < 4; ++n)
            bfr[n] = *(const bf16x8*)&Bs[wc * 64 + n * 16 + lc][g * 8];
#pragma unroll
        for (int m = 0; m < 4; ++m)
#pragma unroll
            for (int n = 0; n < 4; ++n)
                acc[m][n] = mfma16(af[m], bfr[n], acc[m][n]);
        __syncthreads();
    }

    // ---- epilogue. C/D layout: col = lane&15, row = (lane>>4)*4 + reg  [m89/m91]
#pragma unroll
    for (int m = 0; m < 4; ++m) {
#pragma unroll
        for (int n = 0; n < 4; ++n) {
            const int col = wc * 64 + n * 16 + lc;
            const float bv = bias[col];
#pragma unroll
            for (int r = 0; r < 4; ++r) {
                long row = mbase + wr * 64 + m * 16 + g * 4 + r;
                float v = acc[m][n][r] + bv;
                if constexpr (MODE != 2) v = fmaxf(v, 0.f);
                if constexpr (MODE == 0) {
                    // scatter into per-head layout [(bt*8+h)][512][16]
                    long bt = row >> 9, nn = row & 511;
                    long dst = ((bt * 8 + (col >> 4)) * 512 + nn) * 16 + (col & 15);
                    ((u16*)Out)[dst] = f2bf(v);
                } else if constexpr (MODE == 1) {
                    ((u16*)Out)[row * 128 + col] = f2bf(v);
                } else {
                    ((float*)Out)[row * 128 + col] = v;
                }
            }
        }
    }
}

// ---------------------------------------------------------------------------
// Flash attention per (qtile=128 rows, head, bt). 4 waves x 32 q-rows each.
// K padded d:16->32 in LDS (pad zeroed so MFMA sees 0*0, never 0*NaN).
// ---------------------------------------------------------------------------
__global__ __launch_bounds__(256) void attn_k(const u16* __restrict__ qb,
                                              const u16* __restrict__ kb,
                                              const u16* __restrict__ vb,
                                              u16* __restrict__ ob)
{
    // LDS partition (single blob keeps Ks overflow-read inside allocated LDS):
    // Ks [512][24]  (24576 u16)  -- K rows, cols 0..15 data, 16..23 zero
    // Vt [16][520]  ( 8320 u16)  -- V transposed, padded stride vs bank conflicts
    // Ps [4][2][16][72] (9216 u16) -- per-wave P round-trip buffers
    __shared__ u16 smem[29824];
    u16 (*Ks)[24]         = reinterpret_cast<u16(*)[24]>(smem);
    u16 (*Vt)[520]        = reinterpret_cast<u16(*)[520]>(smem + 512 * 24);
    u16 (*Ps)[2][16][72]  = reinterpret_cast<u16(*)[2][16][72]>(smem + 512 * 24 + 16 * 520);

    const int tid  = threadIdx.x;
    const int wave = tid >> 6;
    const int lane = tid & 63;
    const int g    = lane >> 4;
    const int lc   = lane & 15;
    const int qt = blockIdx.x, h = blockIdx.y, bt = blockIdx.z;
    const long hbase = ((long)(bt * 8 + h)) * (512 * 16);

    const u16x8 ZU8 = {0, 0, 0, 0, 0, 0, 0, 0};
    const bf16x8 zf = __builtin_bit_cast(bf16x8, ZU8);
    const f32x4 ZERO4 = {0.f, 0.f, 0.f, 0.f};

    // ---- stage K (coalesced 16B loads) + zero the d=16..23 pad
#pragma unroll
    for (int i = 0; i < 4; ++i) {
        int pos = tid + i * 256;          // 0..1023
        int row = pos >> 1, half = pos & 1;
        *(u16x8*)&Ks[row][half * 8] = *(const u16x8*)(kb + hbase + row * 16 + half * 8);
    }
#pragma unroll
    for (int i = 0; i < 2; ++i) {
        int row = tid + i * 256;          // 0..511
        *(u16x8*)&Ks[row][16] = ZU8;
    }
    // ---- stage V transposed: Vt[c][n] = V[n][c]
#pragma unroll
    for (int i = 0; i < 32; ++i) {
        int pos = tid + i * 256;          // 0..8191
        int c = pos & 15, n = pos >> 4;
        Vt[c][n] = vb[hbase + n * 16 + c];
    }

    // ---- Q fragments (A-frag: row=lane&15, k=8*(lane>>4)+j; k>=16 zero-padded)
    const int qrow0 = qt * 128 + wave * 32;
    bf16x8 qf[2];
#pragma unroll
    for (int mt = 0; mt < 2; ++mt) {
        if (g < 2)
            qf[mt] = *(const bf16x8*)(qb + hbase + (qrow0 + mt * 16 + lc) * 16 + g * 8);
        else
            qf[mt] = zf;
    }

    float m_r[2][4], l_r[2][4];
    f32x4 oacc[2];
#pragma unroll
    for (int mt = 0; mt < 2; ++mt) {
        oacc[mt] = ZERO4;
#pragma unroll
        for (int r = 0; r < 4; ++r) { m_r[mt][r] = -1e30f; l_r[mt][r] = 0.f; }
    }

    __syncthreads();

    for (int ch = 0; ch < 8; ++ch) {
        // ---- S = (Q K^T) for 4 key-tiles of 16
        f32x4 s[2][4];
#pragma unroll
        for (int nt = 0; nt < 4; ++nt) {
            bf16x8 kf = *(const bf16x8*)&Ks[ch * 64 + nt * 16 + lc][g * 8];
#pragma unroll
            for (int mt = 0; mt < 2; ++mt)
                s[mt][nt] = mfma16(qf[mt], kf, ZERO4);
        }
        // ---- online softmax (f32), rows 4g+r live in lane group g
#pragma unroll
        for (int mt = 0; mt < 2; ++mt) {
#pragma unroll
            for (int r = 0; r < 4; ++r) {
                float mx = -1e30f;
#pragma unroll
                for (int nt = 0; nt < 4; ++nt) {
                    s[mt][nt][r] *= 0.25f;                    // 1/sqrt(16)
                    mx = fmaxf(mx, s[mt][nt][r]);
                }
                mx = fmaxf(mx, __shfl_xor(mx, 1));
                mx = fmaxf(mx, __shfl_xor(mx, 2));
                mx = fmaxf(mx, __shfl_xor(mx, 4));
                mx = fmaxf(mx, __shfl_xor(mx, 8));
                float mnew  = fmaxf(m_r[mt][r], mx);
                float alpha = __expf(m_r[mt][r] - mnew);
                m_r[mt][r]  = mnew;
                float rs = 0.f;
#pragma unroll
                for (int nt = 0; nt < 4; ++nt) {
                    float p = __expf(s[mt][nt][r] - mnew);
                    s[mt][nt][r] = p;
                    rs += p;
                }
                rs += __shfl_xor(rs, 1);
                rs += __shfl_xor(rs, 2);
                rs += __shfl_xor(rs, 4);
                rs += __shfl_xor(rs, 8);
                l_r[mt][r] = l_r[mt][r] * alpha + rs;
                oacc[mt][r] *= alpha;
            }
            // write P (C-layout) to per-wave LDS for A-frag re-read
#pragma unroll
            for (int nt = 0; nt < 4; ++nt)
#pragma unroll
                for (int r = 0; r < 4; ++r)
                    Ps[wave][mt][g * 4 + r][nt * 16 + lc] = f2bf(s[mt][nt][r]);
        }
        __syncthreads();
        // ---- O += P V  (2 K-steps of 32 keys)
#pragma unroll
        for (int mt = 0; mt < 2; ++mt) {
#pragma unroll
            for (int ks = 0; ks < 2; ++ks) {
                bf16x8 pf = *(const bf16x8*)&Ps[wave][mt][lc][ks * 32 + g * 8];
                bf16x8 vf = *(const bf16x8*)&Vt[lc][ch * 64 + ks * 32 + g * 8];
                oacc[mt] = mfma16(pf, vf, oacc[mt]);
            }
        }
        __syncthreads();
    }

    // ---- write O, merged-head layout [24576][128]
#pragma unroll
    for (int mt = 0; mt < 2; ++mt) {
#pragma unroll
        for (int r = 0; r < 4; ++r) {
            int row = qrow0 + mt * 16 + g * 4 + r;        // token 0..511
            long mrow = (long)bt * 512 + row;
            float v = oacc[mt][r] / l_r[mt][r];
            ob[mrow * 128 + h * 16 + lc] = f2bf(v);
        }
    }
}

extern "C" void kernel_launch(void* const* d_in, const int* in_sizes, int n_in,
                              void* d_out, int out_size, void* d_ws, size_t ws_size,
                              hipStream_t stream)
{
    const float* x   = (const float*)d_in[0];
    const float* ste = (const float*)d_in[1];
    const float* Wq  = (const float*)d_in[2];
    const float* bq  = (const float*)d_in[3];
    const float* Wk  = (const float*)d_in[4];
    const float* bk  = (const float*)d_in[5];
    const float* Wv  = (const float*)d_in[6];
    const float* bv  = (const float*)d_in[7];
    const float* Wo1 = (const float*)d_in[8];
    const float* bo1 = (const float*)d_in[9];
    const float* Wo2 = (const float*)d_in[10];
    const float* bo2 = (const float*)d_in[11];
    float* out = (float*)d_out;

    const long MTOT = 24576;                 // B*T*N tokens
    u16* qbuf = (u16*)d_ws;                  // per-head [384][512][16] bf16
    u16* kbuf = qbuf + MTOT * 128;
    u16* vbuf = kbuf + MTOT * 128;
    u16* obuf = vbuf + MTOT * 128;           // merged [24576][128] bf16
    u16* hbuf = qbuf;                        // reuse q region after attention

    dim3 blk(256);
    gemm_k<0><<<dim3(192), blk, 0, stream>>>(x, ste, Wq, bq, qbuf);
    gemm_k<0><<<dim3(192), blk, 0, stream>>>(x, ste, Wk, bk, kbuf);
    gemm_k<0><<<dim3(192), blk, 0, stream>>>(x, ste, Wv, bv, vbuf);
    attn_k<<<dim3(4, 8, 48), blk, 0, stream>>>(qbuf, kbuf, vbuf, obuf);
    gemm_k<1><<<dim3(192), blk, 0, stream>>>(obuf, nullptr, Wo1, bo1, hbuf);
    gemm_k<2><<<dim3(192), blk, 0, stream>>>(hbuf, nullptr, Wo2, bo2, out);
}